// Round 10
// baseline (121.061 us; speedup 1.0000x reference)
//
#include <hip/hip_runtime.h>
#include <cstdint>
#include <cstddef>

// ---------------- types & helpers ----------------
typedef __bf16 bf16x8 __attribute__((ext_vector_type(8)));
typedef float  f32x4  __attribute__((ext_vector_type(4)));
typedef unsigned short ushort8_t __attribute__((ext_vector_type(8)));

__device__ __forceinline__ unsigned short f2bf(float f){
  unsigned u = __builtin_bit_cast(unsigned, f);
  u += 0x7fffu + ((u >> 16) & 1u);
  return (unsigned short)(u >> 16);
}
__device__ __forceinline__ float bf2f(unsigned short s){
  return __builtin_bit_cast(float, ((unsigned)s) << 16);
}

#define MFMA16(a,b,c) __builtin_amdgcn_mfma_f32_16x16x32_bf16((a),(b),(c),0,0,0)

__device__ __forceinline__ void gload16(const void* g, void* lds){
  __builtin_amdgcn_global_load_lds(
      (const __attribute__((address_space(1))) void*)g,
      (__attribute__((address_space(3))) void*)lds, 16, 0, 0);
}

// ---------------- workspace layout (ushort element offsets) ----------------
#define E_XW    ((size_t)0)                          // word bf16 (2048x1024)
#define E_XS    (E_XW    + (size_t)2048*1024)        // speaker bf16
#define E_WWORD (E_XS    + (size_t)2048*1024)        // [qw_w; kw_w; v_w] (3072x1024)
#define E_WSPK  (E_WWORD + (size_t)3072*1024)        // [qs_w; ks_w] (2048x1024)
#define E_WOUT  (E_WSPK  + (size_t)2048*1024)        // out_w (1024x1024)
#define E_PWORD (E_WOUT  + (size_t)1024*1024)        // proj word (2048x3072): qw|kw|v
#define E_PSPK  (E_PWORD + (size_t)2048*3072)        // proj spk  (2048x2048): qs|ks
#define E_VT    (E_PSPK  + (size_t)2048*2048)        // V^T (32 heads x 64 x 1024)
#define E_CTX   (E_VT    + (size_t)2048*1024)        // ctx bf16 (2048x1024)
#define E_END   (E_CTX   + (size_t)2048*1024)

// ---------------- 0) fp32 -> bf16 conversion + rope tables + bias concat ----------------
__global__ __launch_bounds__(256) void convert_all(
    const float* __restrict__ word, const float* __restrict__ spk,
    const float* __restrict__ qww,  const float* __restrict__ kww,
    const float* __restrict__ vw,   const float* __restrict__ qsw,
    const float* __restrict__ ksw,  const float* __restrict__ outw,
    const float* __restrict__ qwb,  const float* __restrict__ kwb,
    const float* __restrict__ vb,   const float* __restrict__ qsb,
    const float* __restrict__ ksb,
    unsigned short* __restrict__ wsb, float* __restrict__ FB)
{
  int idx = blockIdx.x*256 + threadIdx.x;
  if (idx < 32768){
    int pos = idx >> 5, i = idx & 31;
    float inv = expf((float)(2*i) * -0.14391157f);   // exp(2i * -ln(1e4)/64)
    float ang = (float)pos * inv;
    float sv, cv; sincosf(ang, &sv, &cv);
    FB[5120 + idx]         = sv;   // TS
    FB[5120 + 32768 + idx] = cv;   // TC
  } else if (idx < 33792){
    int i = idx - 32768;
    FB[i] = qwb[i]; FB[1024+i] = kwb[i]; FB[2048+i] = vb[i];
    FB[3072+i] = qsb[i]; FB[3072+1024+i] = ksb[i];
  }

  const size_t total = 2621440;  // float4 chunks
  for (size_t c = (size_t)blockIdx.x*256 + threadIdx.x; c < total;
       c += (size_t)gridDim.x*256){
    const float* src; size_t dst; size_t i;
    if (c < 524288)       { src = word; dst = E_XW; i = c; }
    else if (c < 1048576) { src = spk;  dst = E_XS; i = c - 524288; }
    else {
      size_t t = c - 1048576; int seg = (int)(t >> 18); i = t & 262143;
      switch (seg){
        case 0:  src = qww; dst = E_WWORD;                      break;
        case 1:  src = kww; dst = E_WWORD + (size_t)1048576;    break;
        case 2:  src = vw;  dst = E_WWORD + (size_t)2097152;    break;
        case 3:  src = qsw; dst = E_WSPK;                       break;
        case 4:  src = ksw; dst = E_WSPK  + (size_t)1048576;    break;
        default: src = outw; dst = E_WOUT;                      break;
      }
    }
    float4 v = ((const float4*)src)[i];
    ushort4 o; o.x = f2bf(v.x); o.y = f2bf(v.y); o.z = f2bf(v.z); o.w = f2bf(v.w);
    ((ushort4*)(wsb + dst))[i] = o;
  }
}

// ---------------- 1) bf16 GEMM body (single-buffered m97 structure) ----------------
// C[m][n] = sum_k A[m][k]*B[n][k] + bias[n].  128 x (NF*32) tile, BK=32.
template<int NF>
__device__ __forceinline__ void gemm_body(
    const unsigned short* __restrict__ A, const unsigned short* __restrict__ Bw,
    const float* __restrict__ bias, void* __restrict__ Cv,
    int N, int bid, int out_bf16,
    unsigned short* As, unsigned short* Bs)
{
  const int K = 1024;
  const int BN = NF*32;
  const int nbn = N / BN;
  const int bm = bid / nbn, bn = bid % nbn;
  const int tid = threadIdx.x;
  const int l = tid & 63, w = tid >> 6;
  const int wm = w >> 1, wn = w & 1;
  const int li = l & 15, lg = l >> 4;

  f32x4 acc[4][NF];
  #pragma unroll
  for (int a = 0; a < 4; a++)
    #pragma unroll
    for (int b = 0; b < NF; b++) acc[a][b] = (f32x4){0.f,0.f,0.f,0.f};

  const int colS = (l & 3) * 8;
  const size_t aBase = (size_t)(bm*128) * K;
  const size_t bBase = (size_t)(bn*BN) * K;

  for (int kt = 0; kt < K; kt += 32){
    #pragma unroll
    for (int j = 0; j < 2; j++){
      int row = (w*2 + j)*16 + (l >> 2);
      gload16(A + aBase + (size_t)row*K + kt + colS, &As[(size_t)(w*2+j)*512]);
    }
    if (NF == 4){
      #pragma unroll
      for (int j = 0; j < 2; j++){
        int row = (w*2 + j)*16 + (l >> 2);
        gload16(Bw + bBase + (size_t)row*K + kt + colS, &Bs[(size_t)(w*2+j)*512]);
      }
    } else {
      int row = w*16 + (l >> 2);
      gload16(Bw + bBase + (size_t)row*K + kt + colS, &Bs[(size_t)w*512]);
    }
    asm volatile("s_waitcnt vmcnt(0)" ::: "memory");
    __syncthreads();

    bf16x8 af[4], bfr[NF];
    const int ko = lg * 8;
    #pragma unroll
    for (int fm = 0; fm < 4; fm++)
      af[fm] = *(const bf16x8*)&As[(wm*64 + fm*16 + li)*32 + ko];
    #pragma unroll
    for (int fn = 0; fn < NF; fn++)
      bfr[fn] = *(const bf16x8*)&Bs[(wn*(NF*16) + fn*16 + li)*32 + ko];
    #pragma unroll
    for (int fm = 0; fm < 4; fm++)
      #pragma unroll
      for (int fn = 0; fn < NF; fn++)
        acc[fm][fn] = MFMA16(af[fm], bfr[fn], acc[fm][fn]);
    __syncthreads();
  }

  #pragma unroll
  for (int fm = 0; fm < 4; fm++){
    int m0 = bm*128 + wm*64 + fm*16 + lg*4;
    #pragma unroll
    for (int fn = 0; fn < NF; fn++){
      int n = bn*BN + wn*(NF*16) + fn*16 + li;
      float bv = bias[n];
      #pragma unroll
      for (int r = 0; r < 4; r++){
        float v = acc[fm][fn][r] + bv;
        if (out_bf16) ((unsigned short*)Cv)[(size_t)(m0+r)*N + n] = f2bf(v);
        else          ((float*)Cv)[(size_t)(m0+r)*N + n] = v;
      }
    }
  }
}

// word (384 tiles, N=3072) + speaker (256 tiles, N=2048): 640 blocks, XCD-swizzled
__global__ __launch_bounds__(256) void gemm_qkv(
    const unsigned short* __restrict__ XW, const unsigned short* __restrict__ WWORD,
    const unsigned short* __restrict__ XS, const unsigned short* __restrict__ WSPK,
    const float* __restrict__ FB,
    unsigned short* __restrict__ PWORD, unsigned short* __restrict__ PSPK)
{
  __shared__ unsigned short As[128*32];
  __shared__ unsigned short Bs[128*32];
  int raw = blockIdx.x;
  int bid = (raw & 7)*80 + (raw >> 3);   // 640 blocks: bijective XCD swizzle (T1)
  if (bid < 384)
    gemm_body<4>(XW, WWORD, FB,        PWORD, 3072, bid,       1, As, Bs);
  else
    gemm_body<4>(XS, WSPK,  FB + 3072, PSPK,  2048, bid - 384, 1, As, Bs);
}

// output projection: 128x64 tiles, 256 blocks, XCD-swizzled
__global__ __launch_bounds__(256) void gemm_out(
    const unsigned short* __restrict__ CTX, const unsigned short* __restrict__ WOUT,
    const float* __restrict__ outb, float* __restrict__ outp)
{
  __shared__ unsigned short As[128*32];
  __shared__ unsigned short Bs[64*32];
  int raw = blockIdx.x;
  int bid = (raw & 7)*32 + (raw >> 3);   // 256 blocks
  gemm_body<2>(CTX, WOUT, outb, outp, 1024, bid, 0, As, Bs);
}

// ---------------- 2) rotary+LN (vectorized, table) + V transpose, one dispatch ----------------
__global__ __launch_bounds__(256) void postproc(
    unsigned short* __restrict__ Pw, unsigned short* __restrict__ Ps,
    const float* __restrict__ gamma, const float* __restrict__ beta,
    const float* __restrict__ TS, const float* __restrict__ TC,
    unsigned short* __restrict__ VT)
{
  __shared__ float lds[2320];
  int bx = blockIdx.x;
  int t = threadIdx.x;
  if (bx < 4096){
    int sec = bx & 3, rp = bx >> 2;
    int half = t >> 7, c = t & 127;
    int row = rp*2 + half;
    int seg = c >> 3, j = c & 7;
    unsigned short* p;
    if      (sec == 0) p = Pw + (size_t)row*3072 +        seg*64;
    else if (sec == 1) p = Pw + (size_t)row*3072 + 1024 + seg*64;
    else if (sec == 2) p = Ps + (size_t)row*2048 +        seg*64;
    else               p = Ps + (size_t)row*2048 + 1024 + seg*64;
    int pos = row & 1023;
    int sl  = half*16 + seg;

    ushort8_t xv = *(const ushort8_t*)(p + j*8);
    float4 sv = *(const float4*)&TS[pos*32 + j*4];
    float4 cv = *(const float4*)&TC[pos*32 + j*4];
    float ss[4] = {sv.x, sv.y, sv.z, sv.w};
    float cc[4] = {cv.x, cv.y, cv.z, cv.w};
    float y1[4], y2[4];
    #pragma unroll
    for (int k = 0; k < 4; k++){
      float x0 = bf2f(xv[2*k]), x1 = bf2f(xv[2*k+1]);
      y1[k] = x0*cc[k] - x1*ss[k];
      y2[k] = x0*ss[k] + x1*cc[k];
    }
    *(float4*)&lds[sl*68 + j*4]      = (float4){y1[0], y1[1], y1[2], y1[3]};
    *(float4*)&lds[sl*68 + 32 + j*4] = (float4){y2[0], y2[1], y2[2], y2[3]};
    __syncthreads();

    float4 a0 = *(const float4*)&lds[sl*68 + j*8];
    float4 a1 = *(const float4*)&lds[sl*68 + j*8 + 4];
    float v[8] = {a0.x, a0.y, a0.z, a0.w, a1.x, a1.y, a1.z, a1.w};
    float s = 0.f;
    #pragma unroll
    for (int k = 0; k < 8; k++) s += v[k];
    #pragma unroll
    for (int o = 1; o < 8; o <<= 1) s += __shfl_xor(s, o);
    float mu = s * (1.f/64.f);
    float sq = 0.f;
    #pragma unroll
    for (int k = 0; k < 8; k++){ float d = v[k] - mu; sq += d*d; }
    #pragma unroll
    for (int o = 1; o < 8; o <<= 1) sq += __shfl_xor(sq, o);
    float rs = rsqrtf(sq * (1.f/64.f) + 1e-5f);
    float4 g0 = *(const float4*)&gamma[j*8], g1 = *(const float4*)&gamma[j*8+4];
    float4 b0 = *(const float4*)&beta[j*8],  b1 = *(const float4*)&beta[j*8+4];
    float gg[8] = {g0.x,g0.y,g0.z,g0.w,g1.x,g1.y,g1.z,g1.w};
    float bb[8] = {b0.x,b0.y,b0.z,b0.w,b1.x,b1.y,b1.z,b1.w};
    ushort8_t o8;
    #pragma unroll
    for (int k = 0; k < 8; k++) o8[k] = f2bf((v[k]-mu)*rs*gg[k] + bb[k]);
    *(ushort8_t*)(p + j*8) = o8;
  } else {
    unsigned short* tp = (unsigned short*)lds;   // 64 x 72
    int bid2 = bx - 4096;
    int bh = bid2 >> 4, lt = bid2 & 15;
    int b = bh >> 4, h = bh & 15;
    #pragma unroll
    for (int i = 0; i < 2; i++){
      int cc2 = t + i*256;
      int row = cc2 >> 3, co = (cc2 & 7)*8;
      const unsigned short* src = Pw + (size_t)(b*1024 + lt*64 + row)*3072 + 2048 + h*64 + co;
      *(uint4*)&tp[row*72 + co] = *(const uint4*)src;
    }
    __syncthreads();
    int d = t >> 2, jb = (t & 3)*16;
    unsigned short o[16];
    #pragma unroll
    for (int j = 0; j < 16; j++) o[j] = tp[(jb + j)*72 + d];
    unsigned short* dst = VT + ((size_t)bh*64 + d)*1024 + lt*64 + jb;
    *(uint4*)dst       = *(uint4*)&o[0];
    *(uint4*)(dst + 8) = *(uint4*)&o[8];
  }
}

// ---------------- 3) fused attention: 512 blocks x 4 waves, XCD-swizzled ----------------
// block -> (b,h,qt) with qt descending; each XCD owns 4 complete (b,h) groups.
// Fixed-max softmax (LN-bounded scores); sweep1 = row sums, sweep2 = recompute+write+PV.
__global__ __launch_bounds__(256) void attn_fused(
    const unsigned short* __restrict__ Pw, const unsigned short* __restrict__ Ps,
    const unsigned short* __restrict__ VTg,
    float* __restrict__ attn, unsigned short* __restrict__ Ctx)
{
  // ushort offsets: KW[2][64*72] | KS[2][64*72] | VT[2][64*72] | PT[4][16*72]
  __shared__ unsigned short SL[32256];   // 64512 B -> 2 blocks/CU

  int raw = blockIdx.x;
  int bx  = (raw & 7)*64 + (raw >> 3);   // T1 XCD swizzle (512 = 8*64)
  int b = bx >> 8, rem = bx & 255, h = rem >> 4;
  int qt = 15 - (rem & 15);              // descending within each (b,h) group
  int tid = threadIdx.x;
  int w = tid >> 6, l = tid & 63;
  int lg = l >> 4, li = l & 15;
  int q0 = qt*64 + w*16;
  int bh = b*16 + h;

  int sr = tid >> 3, sc = tid & 7;       // stages rows sr and sr+32, chunk sc
  const unsigned short* gKW = Pw + (size_t)(b*1024)*3072 + 1024 + h*64;
  const unsigned short* gKS = Ps + (size_t)(b*1024)*2048 + 1024 + h*64;
  const unsigned short* gVT = VTg + (size_t)bh*64*1024;
  unsigned short* pt = SL + 27648 + w*1152;

  // Q fragments
  bf16x8 aqw[2], aqs[2];
  {
    int q = q0 + li;
    const unsigned short* pqw = Pw + (size_t)(b*1024 + q)*3072 + h*64 + lg*8;
    const unsigned short* pqs = Ps + (size_t)(b*1024 + q)*2048 + h*64 + lg*8;
    aqw[0] = *(const bf16x8*)pqw;  aqw[1] = *(const bf16x8*)(pqw + 32);
    aqs[0] = *(const bf16x8*)pqs;  aqs[1] = *(const bf16x8*)(pqs + 32);
  }
  const float rscale = 0.08838834764831845f;   // 1/sqrt(2*HD)

  uint4 ka0, ka1, kb0, kb1, va0, va1;

  // ---- sweep 1: row sums (fixed max m=0; LN-bounded scores) ----
  float ps4[4] = {0.f, 0.f, 0.f, 0.f};
  ka0 = *(const uint4*)(gKW + (size_t)sr*3072 + sc*8);
  ka1 = *(const uint4*)(gKW + (size_t)(sr+32)*3072 + sc*8);
  kb0 = *(const uint4*)(gKS + (size_t)sr*2048 + sc*8);
  kb1 = *(const uint4*)(gKS + (size_t)(sr+32)*2048 + sc*8);
  *(uint4*)(SL + sr*72 + sc*8) = ka0;
  *(uint4*)(SL + (sr+32)*72 + sc*8) = ka1;
  *(uint4*)(SL + 9216 + sr*72 + sc*8) = kb0;
  *(uint4*)(SL + 9216 + (sr+32)*72 + sc*8) = kb1;

  for (int kt = 0; kt <= qt; ++kt){
    int buf = kt & 1;
    if (kt < qt){
      ka0 = *(const uint4*)(gKW + (size_t)((kt+1)*64 + sr)*3072 + sc*8);
      ka1 = *(const uint4*)(gKW + (size_t)((kt+1)*64 + sr+32)*3072 + sc*8);
      kb0 = *(const uint4*)(gKS + (size_t)((kt+1)*64 + sr)*2048 + sc*8);
      kb1 = *(const uint4*)(gKS + (size_t)((kt+1)*64 + sr+32)*2048 + sc*8);
    }
    __syncthreads();
    {
      const unsigned short* KWt = SL + buf*4608;
      const unsigned short* KSt = SL + 9216 + buf*4608;
      f32x4 s[4];
      #pragma unroll
      for (int fn = 0; fn < 4; fn++){
        s[fn] = (f32x4){0.f,0.f,0.f,0.f};
        int rr = (fn*16 + li)*72;
        bf16x8 k0 = *(const bf16x8*)(KWt + rr + lg*8);
        bf16x8 k1 = *(const bf16x8*)(KWt + rr + 32 + lg*8);
        bf16x8 k2 = *(const bf16x8*)(KSt + rr + lg*8);
        bf16x8 k3 = *(const bf16x8*)(KSt + rr + 32 + lg*8);
        s[fn] = MFMA16(aqw[0], k0, s[fn]);
        s[fn] = MFMA16(aqw[1], k1, s[fn]);
        s[fn] = MFMA16(aqs[0], k2, s[fn]);
        s[fn] = MFMA16(aqs[1], k3, s[fn]);
      }
      #pragma unroll
      for (int r = 0; r < 4; r++){
        int q = q0 + lg*4 + r;
        #pragma unroll
        for (int fn = 0; fn < 4; fn++){
          int k = kt*64 + fn*16 + li;
          float e = __expf(s[fn][r] * rscale);
          ps4[r] += (k <= q) ? e : 0.f;
        }
      }
    }
    if (kt < qt){
      int nb = buf ^ 1;
      *(uint4*)(SL + nb*4608 + sr*72 + sc*8) = ka0;
      *(uint4*)(SL + nb*4608 + (sr+32)*72 + sc*8) = ka1;
      *(uint4*)(SL + 9216 + nb*4608 + sr*72 + sc*8) = kb0;
      *(uint4*)(SL + 9216 + nb*4608 + (sr+32)*72 + sc*8) = kb1;
    }
  }
  #pragma unroll
  for (int r = 0; r < 4; r++){
    #pragma unroll
    for (int o = 1; o < 16; o <<= 1) ps4[r] += __shfl_xor(ps4[r], o);
  }
  float rinv[4];
  #pragma unroll
  for (int r = 0; r < 4; r++) rinv[r] = 1.f / ps4[r];

  // ---- sweep 2: recompute, normalize, write attn, PV ----
  __syncthreads();
  ka0 = *(const uint4*)(gKW + (size_t)sr*3072 + sc*8);
  ka1 = *(const uint4*)(gKW + (size_t)(sr+32)*3072 + sc*8);
  kb0 = *(const uint4*)(gKS + (size_t)sr*2048 + sc*8);
  kb1 = *(const uint4*)(gKS + (size_t)(sr+32)*2048 + sc*8);
  va0 = *(const uint4*)(gVT + (size_t)sr*1024 + sc*8);
  va1 = *(const uint4*)(gVT + (size_t)(sr+32)*1024 + sc*8);
  *(uint4*)(SL + sr*72 + sc*8) = ka0;
  *(uint4*)(SL + (sr+32)*72 + sc*8) = ka1;
  *(uint4*)(SL + 9216 + sr*72 + sc*8) = kb0;
  *(uint4*)(SL + 9216 + (sr+32)*72 + sc*8) = kb1;
  *(uint4*)(SL + 18432 + sr*72 + sc*8) = va0;
  *(uint4*)(SL + 18432 + (sr+32)*72 + sc*8) = va1;

  f32x4 c[4];
  #pragma unroll
  for (int fn = 0; fn < 4; fn++) c[fn] = (f32x4){0.f,0.f,0.f,0.f};

  for (int kt = 0; kt <= qt; ++kt){
    int buf = kt & 1;
    if (kt < qt){
      ka0 = *(const uint4*)(gKW + (size_t)((kt+1)*64 + sr)*3072 + sc*8);
      ka1 = *(const uint4*)(gKW + (size_t)((kt+1)*64 + sr+32)*3072 + sc*8);
      kb0 = *(const uint4*)(gKS + (size_t)((kt+1)*64 + sr)*2048 + sc*8);
      kb1 = *(const uint4*)(gKS + (size_t)((kt+1)*64 + sr+32)*2048 + sc*8);
      va0 = *(const uint4*)(gVT + (size_t)sr*1024 + (kt+1)*64 + sc*8);
      va1 = *(const uint4*)(gVT + (size_t)(sr+32)*1024 + (kt+1)*64 + sc*8);
    }
    __syncthreads();
    float* abase = attn + ((size_t)bh*1024 + q0 + li)*1024 + kt*64;
    {
      const unsigned short* KWt = SL + buf*4608;
      const unsigned short* KSt = SL + 9216 + buf*4608;
      const unsigned short* VTt = SL + 18432 + buf*4608;
      f32x4 s[4];
      #pragma unroll
      for (int fn = 0; fn < 4; fn++){
        s[fn] = (f32x4){0.f,0.f,0.f,0.f};
        int rr = (fn*16 + li)*72;
        bf16x8 k0 = *(const bf16x8*)(KWt + rr + lg*8);
        bf16x8 k1 = *(const bf16x8*)(KWt + rr + 32 + lg*8);
        bf16x8 k2 = *(const bf16x8*)(KSt + rr + lg*8);
        bf16x8 k3 = *(const bf16x8*)(KSt + rr + 32 + lg*8);
        s[fn] = MFMA16(aqw[0], k0, s[fn]);
        s[fn] = MFMA16(aqw[1], k1, s[fn]);
        s[fn] = MFMA16(aqs[0], k2, s[fn]);
        s[fn] = MFMA16(aqs[1], k3, s[fn]);
      }
      #pragma unroll
      for (int fn = 0; fn < 4; fn++){
        #pragma unroll
        for (int r = 0; r < 4; r++){
          int k = kt*64 + fn*16 + li;
          int q = q0 + lg*4 + r;
          float pp = (k <= q) ? __expf(s[fn][r] * rscale) * rinv[r] : 0.f;
          pt[(lg*4 + r)*72 + fn*16 + li] = f2bf(pp);
        }
      }
      asm volatile("s_waitcnt lgkmcnt(0)" ::: "memory");
      __builtin_amdgcn_sched_barrier(0);
      bf16x8 af0 = *(const bf16x8*)(pt + li*72 + lg*8);
      bf16x8 af1 = *(const bf16x8*)(pt + li*72 + 32 + lg*8);
      ushort8_t u0 = __builtin_bit_cast(ushort8_t, af0);
      ushort8_t u1 = __builtin_bit_cast(ushort8_t, af1);
      *(float4*)(abase + lg*8)          = (float4){bf2f(u0[0]),bf2f(u0[1]),bf2f(u0[2]),bf2f(u0[3])};
      *(float4*)(abase + lg*8 + 4)      = (float4){bf2f(u0[4]),bf2f(u0[5]),bf2f(u0[6]),bf2f(u0[7])};
      *(float4*)(abase + 32 + lg*8)     = (float4){bf2f(u1[0]),bf2f(u1[1]),bf2f(u1[2]),bf2f(u1[3])};
      *(float4*)(abase + 32 + lg*8 + 4) = (float4){bf2f(u1[4]),bf2f(u1[5]),bf2f(u1[6]),bf2f(u1[7])};
      #pragma unroll
      for (int fn = 0; fn < 4; fn++){
        int rr = (fn*16 + li)*72;
        bf16x8 v0 = *(const bf16x8*)(VTt + rr + lg*8);
        bf16x8 v1 = *(const bf16x8*)(VTt + rr + 32 + lg*8);
        c[fn] = MFMA16(af0, v0, c[fn]);
        c[fn] = MFMA16(af1, v1, c[fn]);
      }
    }
    if (kt < qt){
      int nb = buf ^ 1;
      *(uint4*)(SL + nb*4608 + sr*72 + sc*8) = ka0;
      *(uint4*)(SL + nb*4608 + (sr+32)*72 + sc*8) = ka1;
      *(uint4*)(SL + 9216 + nb*4608 + sr*72 + sc*8) = kb0;
      *(uint4*)(SL + 9216 + nb*4608 + (sr+32)*72 + sc*8) = kb1;
      *(uint4*)(SL + 18432 + nb*4608 + sr*72 + sc*8) = va0;
      *(uint4*)(SL + 18432 + nb*4608 + (sr+32)*72 + sc*8) = va1;
    }
  }

  // zero-fill upper triangle tiles (no sync needed)
  for (int kt = qt + 1; kt < 16; ++kt){
    float* abase = attn + ((size_t)bh*1024 + q0 + li)*1024 + kt*64;
    float4 z = {0.f, 0.f, 0.f, 0.f};
    *(float4*)(abase + lg*8)          = z;
    *(float4*)(abase + lg*8 + 4)      = z;
    *(float4*)(abase + 32 + lg*8)     = z;
    *(float4*)(abase + 32 + lg*8 + 4) = z;
  }

  // ctx write: D layout row=(l>>4)*4+r, col=l&15  (re-read by gemm_out -> keep cached)
  #pragma unroll
  for (int fn = 0; fn < 4; fn++){
    #pragma unroll
    for (int r = 0; r < 4; r++){
      int q = q0 + lg*4 + r;
      int d = fn*16 + li;
      Ctx[(size_t)(b*1024 + q)*1024 + h*64 + d] = f2bf(c[fn][r]);
    }
  }
}

// ---------------- host launch ----------------
extern "C" void kernel_launch(void* const* d_in, const int* in_sizes, int n_in,
                              void* d_out, int out_size, void* d_ws, size_t ws_size,
                              hipStream_t stream)
{
  (void)in_sizes; (void)n_in; (void)out_size; (void)ws_size;
  const float* word = (const float*)d_in[0];
  const float* spk  = (const float*)d_in[1];
  const float* qww  = (const float*)d_in[3];
  const float* qwb  = (const float*)d_in[4];
  const float* kww  = (const float*)d_in[5];
  const float* kwb  = (const float*)d_in[6];
  const float* qsw  = (const float*)d_in[7];
  const float* qsb  = (const float*)d_in[8];
  const float* ksw  = (const float*)d_in[9];
  const float* ksb  = (const float*)d_in[10];
  const float* vw   = (const float*)d_in[11];
  const float* vb   = (const float*)d_in[12];
  const float* outw = (const float*)d_in[13];
  const float* outb = (const float*)d_in[14];
  const float* gamma= (const float*)d_in[15];
  const float* beta = (const float*)d_in[16];

  unsigned short* U = (unsigned short*)d_ws;
  unsigned short* XW    = U + E_XW;
  unsigned short* XS    = U + E_XS;
  unsigned short* WWORD = U + E_WWORD;
  unsigned short* WSPK  = U + E_WSPK;
  unsigned short* WOUT  = U + E_WOUT;
  unsigned short* PWORD = U + E_PWORD;
  unsigned short* PSPK  = U + E_PSPK;
  unsigned short* VT    = U + E_VT;
  unsigned short* CTX   = U + E_CTX;
  float* FB = (float*)(U + E_END);
  float* TS = FB + 5120;
  float* TC = TS + 32768;

  float* outp = (float*)d_out;
  float* attn = outp + (size_t)2*1024*1024;

  convert_all<<<4096, 256, 0, stream>>>(word, spk, qww, kww, vw, qsw, ksw, outw,
                                        qwb, kwb, vb, qsb, ksb, U, FB);
  gemm_qkv<<<640, 256, 0, stream>>>(XW, WWORD, XS, WSPK, FB, PWORD, PSPK);
  postproc<<<4608, 256, 0, stream>>>(PWORD, PSPK, gamma, beta, TS, TC, VT);
  attn_fused<<<512, 256, 0, stream>>>(PWORD, PSPK, VT, attn, CTX);
  gemm_out<<<256, 256, 0, stream>>>(CTX, WOUT, outb, outp);
}

// Round 11
// 116.664 us; speedup vs baseline: 1.0377x; 1.0377x over previous
//
#include <hip/hip_runtime.h>
#include <cstdint>
#include <cstddef>

// ---------------- types & helpers ----------------
typedef __bf16 bf16x8 __attribute__((ext_vector_type(8)));
typedef float  f32x4  __attribute__((ext_vector_type(4)));
typedef unsigned short ushort8_t __attribute__((ext_vector_type(8)));

__device__ __forceinline__ unsigned short f2bf(float f){
  unsigned u = __builtin_bit_cast(unsigned, f);
  u += 0x7fffu + ((u >> 16) & 1u);
  return (unsigned short)(u >> 16);
}
__device__ __forceinline__ float bf2f(unsigned short s){
  return __builtin_bit_cast(float, ((unsigned)s) << 16);
}

#define MFMA16(a,b,c) __builtin_amdgcn_mfma_f32_16x16x32_bf16((a),(b),(c),0,0,0)

__device__ __forceinline__ void gload16(const void* g, void* lds){
  __builtin_amdgcn_global_load_lds(
      (const __attribute__((address_space(1))) void*)g,
      (__attribute__((address_space(3))) void*)lds, 16, 0, 0);
}

// ---------------- workspace layout (ushort element offsets) ----------------
#define E_XW    ((size_t)0)                          // word bf16 (2048x1024)
#define E_XS    (E_XW    + (size_t)2048*1024)        // speaker bf16
#define E_WWORD (E_XS    + (size_t)2048*1024)        // [qw_w; kw_w; v_w] (3072x1024)
#define E_WSPK  (E_WWORD + (size_t)3072*1024)        // [qs_w; ks_w] (2048x1024)
#define E_WOUT  (E_WSPK  + (size_t)2048*1024)        // out_w (1024x1024)
#define E_PWORD (E_WOUT  + (size_t)1024*1024)        // proj word (2048x3072): qw|kw|v
#define E_PSPK  (E_PWORD + (size_t)2048*3072)        // proj spk  (2048x2048): qs|ks
#define E_VT    (E_PSPK  + (size_t)2048*2048)        // V^T (32 heads x 64 x 1024)
#define E_CTX   (E_VT    + (size_t)2048*1024)        // ctx bf16 (2048x1024)
#define E_END   (E_CTX   + (size_t)2048*1024)

// ---------------- 0) fp32 -> bf16 conversion + rope tables + bias concat ----------------
__global__ __launch_bounds__(256) void convert_all(
    const float* __restrict__ word, const float* __restrict__ spk,
    const float* __restrict__ qww,  const float* __restrict__ kww,
    const float* __restrict__ vw,   const float* __restrict__ qsw,
    const float* __restrict__ ksw,  const float* __restrict__ outw,
    const float* __restrict__ qwb,  const float* __restrict__ kwb,
    const float* __restrict__ vb,   const float* __restrict__ qsb,
    const float* __restrict__ ksb,
    unsigned short* __restrict__ wsb, float* __restrict__ FB)
{
  int idx = blockIdx.x*256 + threadIdx.x;
  if (idx < 32768){
    int pos = idx >> 5, i = idx & 31;
    float inv = expf((float)(2*i) * -0.14391157f);   // exp(2i * -ln(1e4)/64)
    float ang = (float)pos * inv;
    float sv, cv; sincosf(ang, &sv, &cv);
    FB[5120 + idx]         = sv;   // TS
    FB[5120 + 32768 + idx] = cv;   // TC
  } else if (idx < 33792){
    int i = idx - 32768;
    FB[i] = qwb[i]; FB[1024+i] = kwb[i]; FB[2048+i] = vb[i];
    FB[3072+i] = qsb[i]; FB[3072+1024+i] = ksb[i];
  }

  const size_t total = 2621440;  // float4 chunks
  for (size_t c = (size_t)blockIdx.x*256 + threadIdx.x; c < total;
       c += (size_t)gridDim.x*256){
    const float* src; size_t dst; size_t i;
    if (c < 524288)       { src = word; dst = E_XW; i = c; }
    else if (c < 1048576) { src = spk;  dst = E_XS; i = c - 524288; }
    else {
      size_t t = c - 1048576; int seg = (int)(t >> 18); i = t & 262143;
      switch (seg){
        case 0:  src = qww; dst = E_WWORD;                      break;
        case 1:  src = kww; dst = E_WWORD + (size_t)1048576;    break;
        case 2:  src = vw;  dst = E_WWORD + (size_t)2097152;    break;
        case 3:  src = qsw; dst = E_WSPK;                       break;
        case 4:  src = ksw; dst = E_WSPK  + (size_t)1048576;    break;
        default: src = outw; dst = E_WOUT;                      break;
      }
    }
    float4 v = ((const float4*)src)[i];
    ushort4 o; o.x = f2bf(v.x); o.y = f2bf(v.y); o.z = f2bf(v.z); o.w = f2bf(v.w);
    ((ushort4*)(wsb + dst))[i] = o;
  }
}

// ---------------- 1) bf16 GEMM body (single-buffered m97 structure) ----------------
// C[m][n] = sum_k A[m][k]*B[n][k] + bias[n].  128 x (NF*32) tile, BK=32.
template<int NF>
__device__ __forceinline__ void gemm_body(
    const unsigned short* __restrict__ A, const unsigned short* __restrict__ Bw,
    const float* __restrict__ bias, void* __restrict__ Cv,
    int N, int bid, int out_bf16,
    unsigned short* As, unsigned short* Bs)
{
  const int K = 1024;
  const int BN = NF*32;
  const int nbn = N / BN;
  const int bm = bid / nbn, bn = bid % nbn;
  const int tid = threadIdx.x;
  const int l = tid & 63, w = tid >> 6;
  const int wm = w >> 1, wn = w & 1;
  const int li = l & 15, lg = l >> 4;

  f32x4 acc[4][NF];
  #pragma unroll
  for (int a = 0; a < 4; a++)
    #pragma unroll
    for (int b = 0; b < NF; b++) acc[a][b] = (f32x4){0.f,0.f,0.f,0.f};

  const int colS = (l & 3) * 8;
  const size_t aBase = (size_t)(bm*128) * K;
  const size_t bBase = (size_t)(bn*BN) * K;

  for (int kt = 0; kt < K; kt += 32){
    #pragma unroll
    for (int j = 0; j < 2; j++){
      int row = (w*2 + j)*16 + (l >> 2);
      gload16(A + aBase + (size_t)row*K + kt + colS, &As[(size_t)(w*2+j)*512]);
    }
    if (NF == 4){
      #pragma unroll
      for (int j = 0; j < 2; j++){
        int row = (w*2 + j)*16 + (l >> 2);
        gload16(Bw + bBase + (size_t)row*K + kt + colS, &Bs[(size_t)(w*2+j)*512]);
      }
    } else {
      int row = w*16 + (l >> 2);
      gload16(Bw + bBase + (size_t)row*K + kt + colS, &Bs[(size_t)w*512]);
    }
    asm volatile("s_waitcnt vmcnt(0)" ::: "memory");
    __syncthreads();

    bf16x8 af[4], bfr[NF];
    const int ko = lg * 8;
    #pragma unroll
    for (int fm = 0; fm < 4; fm++)
      af[fm] = *(const bf16x8*)&As[(wm*64 + fm*16 + li)*32 + ko];
    #pragma unroll
    for (int fn = 0; fn < NF; fn++)
      bfr[fn] = *(const bf16x8*)&Bs[(wn*(NF*16) + fn*16 + li)*32 + ko];
    #pragma unroll
    for (int fm = 0; fm < 4; fm++)
      #pragma unroll
      for (int fn = 0; fn < NF; fn++)
        acc[fm][fn] = MFMA16(af[fm], bfr[fn], acc[fm][fn]);
    __syncthreads();
  }

  #pragma unroll
  for (int fm = 0; fm < 4; fm++){
    int m0 = bm*128 + wm*64 + fm*16 + lg*4;
    #pragma unroll
    for (int fn = 0; fn < NF; fn++){
      int n = bn*BN + wn*(NF*16) + fn*16 + li;
      float bv = bias[n];
      #pragma unroll
      for (int r = 0; r < 4; r++){
        float v = acc[fm][fn][r] + bv;
        if (out_bf16) ((unsigned short*)Cv)[(size_t)(m0+r)*N + n] = f2bf(v);
        else          ((float*)Cv)[(size_t)(m0+r)*N + n] = v;
      }
    }
  }
}

// word (384 tiles, N=3072) + speaker (256 tiles, N=2048): 640 blocks, XCD-swizzled
__global__ __launch_bounds__(256) void gemm_qkv(
    const unsigned short* __restrict__ XW, const unsigned short* __restrict__ WWORD,
    const unsigned short* __restrict__ XS, const unsigned short* __restrict__ WSPK,
    const float* __restrict__ FB,
    unsigned short* __restrict__ PWORD, unsigned short* __restrict__ PSPK)
{
  __shared__ unsigned short As[128*32];
  __shared__ unsigned short Bs[128*32];
  int raw = blockIdx.x;
  int bid = (raw & 7)*80 + (raw >> 3);   // 640 blocks: bijective XCD swizzle (T1)
  if (bid < 384)
    gemm_body<4>(XW, WWORD, FB,        PWORD, 3072, bid,       1, As, Bs);
  else
    gemm_body<4>(XS, WSPK,  FB + 3072, PSPK,  2048, bid - 384, 1, As, Bs);
}

// output projection: 128x64 tiles, 256 blocks, XCD-swizzled
__global__ __launch_bounds__(256) void gemm_out(
    const unsigned short* __restrict__ CTX, const unsigned short* __restrict__ WOUT,
    const float* __restrict__ outb, float* __restrict__ outp)
{
  __shared__ unsigned short As[128*32];
  __shared__ unsigned short Bs[64*32];
  int raw = blockIdx.x;
  int bid = (raw & 7)*32 + (raw >> 3);   // 256 blocks
  gemm_body<2>(CTX, WOUT, outb, outp, 1024, bid, 0, As, Bs);
}

// ---------------- 2) rotary+LN (vectorized, table) + V transpose, one dispatch ----------------
__global__ __launch_bounds__(256) void postproc(
    unsigned short* __restrict__ Pw, unsigned short* __restrict__ Ps,
    const float* __restrict__ gamma, const float* __restrict__ beta,
    const float* __restrict__ TS, const float* __restrict__ TC,
    unsigned short* __restrict__ VT)
{
  __shared__ float lds[2320];
  int bx = blockIdx.x;
  int t = threadIdx.x;
  if (bx < 4096){
    int sec = bx & 3, rp = bx >> 2;
    int half = t >> 7, c = t & 127;
    int row = rp*2 + half;
    int seg = c >> 3, j = c & 7;
    unsigned short* p;
    if      (sec == 0) p = Pw + (size_t)row*3072 +        seg*64;
    else if (sec == 1) p = Pw + (size_t)row*3072 + 1024 + seg*64;
    else if (sec == 2) p = Ps + (size_t)row*2048 +        seg*64;
    else               p = Ps + (size_t)row*2048 + 1024 + seg*64;
    int pos = row & 1023;
    int sl  = half*16 + seg;

    ushort8_t xv = *(const ushort8_t*)(p + j*8);
    float4 sv = *(const float4*)&TS[pos*32 + j*4];
    float4 cv = *(const float4*)&TC[pos*32 + j*4];
    float ss[4] = {sv.x, sv.y, sv.z, sv.w};
    float cc[4] = {cv.x, cv.y, cv.z, cv.w};
    float y1[4], y2[4];
    #pragma unroll
    for (int k = 0; k < 4; k++){
      float x0 = bf2f(xv[2*k]), x1 = bf2f(xv[2*k+1]);
      y1[k] = x0*cc[k] - x1*ss[k];
      y2[k] = x0*ss[k] + x1*cc[k];
    }
    *(float4*)&lds[sl*68 + j*4]      = (float4){y1[0], y1[1], y1[2], y1[3]};
    *(float4*)&lds[sl*68 + 32 + j*4] = (float4){y2[0], y2[1], y2[2], y2[3]};
    __syncthreads();

    float4 a0 = *(const float4*)&lds[sl*68 + j*8];
    float4 a1 = *(const float4*)&lds[sl*68 + j*8 + 4];
    float v[8] = {a0.x, a0.y, a0.z, a0.w, a1.x, a1.y, a1.z, a1.w};
    float s = 0.f;
    #pragma unroll
    for (int k = 0; k < 8; k++) s += v[k];
    #pragma unroll
    for (int o = 1; o < 8; o <<= 1) s += __shfl_xor(s, o);
    float mu = s * (1.f/64.f);
    float sq = 0.f;
    #pragma unroll
    for (int k = 0; k < 8; k++){ float d = v[k] - mu; sq += d*d; }
    #pragma unroll
    for (int o = 1; o < 8; o <<= 1) sq += __shfl_xor(sq, o);
    float rs = rsqrtf(sq * (1.f/64.f) + 1e-5f);
    float4 g0 = *(const float4*)&gamma[j*8], g1 = *(const float4*)&gamma[j*8+4];
    float4 b0 = *(const float4*)&beta[j*8],  b1 = *(const float4*)&beta[j*8+4];
    float gg[8] = {g0.x,g0.y,g0.z,g0.w,g1.x,g1.y,g1.z,g1.w};
    float bb[8] = {b0.x,b0.y,b0.z,b0.w,b1.x,b1.y,b1.z,b1.w};
    ushort8_t o8;
    #pragma unroll
    for (int k = 0; k < 8; k++) o8[k] = f2bf((v[k]-mu)*rs*gg[k] + bb[k]);
    *(ushort8_t*)(p + j*8) = o8;
  } else {
    unsigned short* tp = (unsigned short*)lds;   // 64 x 72
    int bid2 = bx - 4096;
    int bh = bid2 >> 4, lt = bid2 & 15;
    int b = bh >> 4, h = bh & 15;
    #pragma unroll
    for (int i = 0; i < 2; i++){
      int cc2 = t + i*256;
      int row = cc2 >> 3, co = (cc2 & 7)*8;
      const unsigned short* src = Pw + (size_t)(b*1024 + lt*64 + row)*3072 + 2048 + h*64 + co;
      *(uint4*)&tp[row*72 + co] = *(const uint4*)src;
    }
    __syncthreads();
    int d = t >> 2, jb = (t & 3)*16;
    unsigned short o[16];
    #pragma unroll
    for (int j = 0; j < 16; j++) o[j] = tp[(jb + j)*72 + d];
    unsigned short* dst = VT + ((size_t)bh*64 + d)*1024 + lt*64 + jb;
    *(uint4*)dst       = *(uint4*)&o[0];
    *(uint4*)(dst + 8) = *(uint4*)&o[8];
  }
}

// ---------------- 3) fused attention: 512 blocks x 8 waves, strip x k-half split ----------------
// block = (b,h,qt); wave w: q-strip = w&3 (16 rows), k-half = w>>2 (32 cols per tile).
// All waves active every kt. Row sums combined via LDS between half-partners; ctx via LDS reduce.
__global__ __launch_bounds__(512) void attn_fused(
    const unsigned short* __restrict__ Pw, const unsigned short* __restrict__ Ps,
    const unsigned short* __restrict__ VTg,
    float* __restrict__ attn, unsigned short* __restrict__ Ctx)
{
  // ushort offsets: KW[2][64*72]=0 | KS[2][64*72]=9216 | VT[2][64*72]=18432 | PT[8][16*72]=27648
  __shared__ unsigned short SL[36864];   // 73728 B -> 2 blocks/CU (16 waves/CU)

  int raw = blockIdx.x;
  int bx  = (raw & 7)*64 + (raw >> 3);   // T1 XCD swizzle (512 = 8*64)
  int b = bx >> 8, rem = bx & 255, h = rem >> 4;
  int qt = 15 - (rem & 15);              // descending within each (b,h) group
  int tid = threadIdx.x;
  int w = tid >> 6, l = tid & 63;
  int ws = w & 3, hf = w >> 2;           // q-strip, k-half
  int lg = l >> 4, li = l & 15;
  int q0 = qt*64 + ws*16;
  int bh = b*16 + h;

  int sr = tid >> 3, sc = tid & 7;       // 512 threads stage 64 rows x 8 chunks, 1 uint4 each
  const unsigned short* gKW = Pw + (size_t)(b*1024)*3072 + 1024 + h*64;
  const unsigned short* gKS = Ps + (size_t)(b*1024)*2048 + 1024 + h*64;
  const unsigned short* gVT = VTg + (size_t)bh*64*1024;
  unsigned short* pt = SL + 27648 + w*1152;
  float* SLf = (float*)(SL + 27648);     // 128-float sum exchange (pt area, between sweeps)
  float* SLc = (float*)SL;               // ctx reduce area (staging area, after sweeps)

  // Q fragments (full d=64; both halves need them)
  bf16x8 aqw[2], aqs[2];
  {
    int q = q0 + li;
    const unsigned short* pqw = Pw + (size_t)(b*1024 + q)*3072 + h*64 + lg*8;
    const unsigned short* pqs = Ps + (size_t)(b*1024 + q)*2048 + h*64 + lg*8;
    aqw[0] = *(const bf16x8*)pqw;  aqw[1] = *(const bf16x8*)(pqw + 32);
    aqs[0] = *(const bf16x8*)pqs;  aqs[1] = *(const bf16x8*)(pqs + 32);
  }
  const float rscale = 0.08838834764831845f;   // 1/sqrt(2*HD)

  uint4 ka, kb, va;

  // ---- sweep 1: row sums (fixed max m=0; LN-bounded scores) ----
  float ps4[4] = {0.f, 0.f, 0.f, 0.f};
  ka = *(const uint4*)(gKW + (size_t)sr*3072 + sc*8);
  kb = *(const uint4*)(gKS + (size_t)sr*2048 + sc*8);
  *(uint4*)(SL + sr*72 + sc*8) = ka;
  *(uint4*)(SL + 9216 + sr*72 + sc*8) = kb;

  for (int kt = 0; kt <= qt; ++kt){
    int buf = kt & 1;
    if (kt < qt){
      ka = *(const uint4*)(gKW + (size_t)((kt+1)*64 + sr)*3072 + sc*8);
      kb = *(const uint4*)(gKS + (size_t)((kt+1)*64 + sr)*2048 + sc*8);
    }
    __syncthreads();
    {
      const unsigned short* KWt = SL + buf*4608;
      const unsigned short* KSt = SL + 9216 + buf*4608;
      f32x4 s[2];
      #pragma unroll
      for (int f = 0; f < 2; f++){
        int fn = hf*2 + f;
        s[f] = (f32x4){0.f,0.f,0.f,0.f};
        int rr = (fn*16 + li)*72;
        bf16x8 k0 = *(const bf16x8*)(KWt + rr + lg*8);
        bf16x8 k1 = *(const bf16x8*)(KWt + rr + 32 + lg*8);
        bf16x8 k2 = *(const bf16x8*)(KSt + rr + lg*8);
        bf16x8 k3 = *(const bf16x8*)(KSt + rr + 32 + lg*8);
        s[f] = MFMA16(aqw[0], k0, s[f]);
        s[f] = MFMA16(aqw[1], k1, s[f]);
        s[f] = MFMA16(aqs[0], k2, s[f]);
        s[f] = MFMA16(aqs[1], k3, s[f]);
      }
      #pragma unroll
      for (int r = 0; r < 4; r++){
        int q = q0 + lg*4 + r;
        #pragma unroll
        for (int f = 0; f < 2; f++){
          int k = kt*64 + (hf*2 + f)*16 + li;
          float e = __expf(s[f][r] * rscale);
          ps4[r] += (k <= q) ? e : 0.f;
        }
      }
    }
    if (kt < qt){
      int nb = buf ^ 1;
      *(uint4*)(SL + nb*4608 + sr*72 + sc*8) = ka;
      *(uint4*)(SL + 9216 + nb*4608 + sr*72 + sc*8) = kb;
    }
  }
  // reduce over li within wave (each wave holds half-sums for its 16 rows)
  #pragma unroll
  for (int r = 0; r < 4; r++){
    #pragma unroll
    for (int o = 1; o < 16; o <<= 1) ps4[r] += __shfl_xor(ps4[r], o);
  }
  // exchange halves via LDS
  __syncthreads();
  if (li == 0){
    #pragma unroll
    for (int r = 0; r < 4; r++) SLf[w*16 + lg*4 + r] = ps4[r];
  }
  __syncthreads();
  float rinv[4];
  #pragma unroll
  for (int r = 0; r < 4; r++)
    rinv[r] = 1.f / (ps4[r] + SLf[(w ^ 4)*16 + lg*4 + r]);

  // ---- sweep 2: recompute, normalize, write attn (own half), PV partial ----
  __syncthreads();
  ka = *(const uint4*)(gKW + (size_t)sr*3072 + sc*8);
  kb = *(const uint4*)(gKS + (size_t)sr*2048 + sc*8);
  va = *(const uint4*)(gVT + (size_t)sr*1024 + sc*8);
  *(uint4*)(SL + sr*72 + sc*8) = ka;
  *(uint4*)(SL + 9216 + sr*72 + sc*8) = kb;
  *(uint4*)(SL + 18432 + sr*72 + sc*8) = va;

  f32x4 c[4];
  #pragma unroll
  for (int fn = 0; fn < 4; fn++) c[fn] = (f32x4){0.f,0.f,0.f,0.f};

  for (int kt = 0; kt <= qt; ++kt){
    int buf = kt & 1;
    if (kt < qt){
      ka = *(const uint4*)(gKW + (size_t)((kt+1)*64 + sr)*3072 + sc*8);
      kb = *(const uint4*)(gKS + (size_t)((kt+1)*64 + sr)*2048 + sc*8);
      va = *(const uint4*)(gVT + (size_t)sr*1024 + (kt+1)*64 + sc*8);
    }
    __syncthreads();
    {
      const unsigned short* KWt = SL + buf*4608;
      const unsigned short* KSt = SL + 9216 + buf*4608;
      const unsigned short* VTt = SL + 18432 + buf*4608;
      f32x4 s[2];
      #pragma unroll
      for (int f = 0; f < 2; f++){
        int fn = hf*2 + f;
        s[f] = (f32x4){0.f,0.f,0.f,0.f};
        int rr = (fn*16 + li)*72;
        bf16x8 k0 = *(const bf16x8*)(KWt + rr + lg*8);
        bf16x8 k1 = *(const bf16x8*)(KWt + rr + 32 + lg*8);
        bf16x8 k2 = *(const bf16x8*)(KSt + rr + lg*8);
        bf16x8 k3 = *(const bf16x8*)(KSt + rr + 32 + lg*8);
        s[f] = MFMA16(aqw[0], k0, s[f]);
        s[f] = MFMA16(aqw[1], k1, s[f]);
        s[f] = MFMA16(aqs[0], k2, s[f]);
        s[f] = MFMA16(aqs[1], k3, s[f]);
      }
      #pragma unroll
      for (int f = 0; f < 2; f++){
        int fn = hf*2 + f;
        #pragma unroll
        for (int r = 0; r < 4; r++){
          int k = kt*64 + fn*16 + li;
          int q = q0 + lg*4 + r;
          float pp = (k <= q) ? __expf(s[f][r] * rscale) * rinv[r] : 0.f;
          pt[(lg*4 + r)*72 + fn*16 + li] = f2bf(pp);
        }
      }
      asm volatile("s_waitcnt lgkmcnt(0)" ::: "memory");
      __builtin_amdgcn_sched_barrier(0);
      bf16x8 af = *(const bf16x8*)(pt + li*72 + hf*32 + lg*8);
      ushort8_t u = __builtin_bit_cast(ushort8_t, af);
      float* abase = attn + ((size_t)bh*1024 + q0 + li)*1024 + kt*64 + hf*32;
      *(float4*)(abase + lg*8)     = (float4){bf2f(u[0]),bf2f(u[1]),bf2f(u[2]),bf2f(u[3])};
      *(float4*)(abase + lg*8 + 4) = (float4){bf2f(u[4]),bf2f(u[5]),bf2f(u[6]),bf2f(u[7])};
      #pragma unroll
      for (int fn2 = 0; fn2 < 4; fn2++){
        int rr = (fn2*16 + li)*72;
        bf16x8 v = *(const bf16x8*)(VTt + rr + hf*32 + lg*8);
        c[fn2] = MFMA16(af, v, c[fn2]);
      }
    }
    if (kt < qt){
      int nb = buf ^ 1;
      *(uint4*)(SL + nb*4608 + sr*72 + sc*8) = ka;
      *(uint4*)(SL + 9216 + nb*4608 + sr*72 + sc*8) = kb;
      *(uint4*)(SL + 18432 + nb*4608 + sr*72 + sc*8) = va;
    }
  }

  // zero-fill upper triangle tiles (own rows, own half)
  for (int kt = qt + 1; kt < 16; ++kt){
    float* abase = attn + ((size_t)bh*1024 + q0 + li)*1024 + kt*64 + hf*32;
    float4 z = {0.f, 0.f, 0.f, 0.f};
    *(float4*)(abase + lg*8)     = z;
    *(float4*)(abase + lg*8 + 4) = z;
  }

  // ---- ctx reduce across half-partners, then write (waves 0-3) ----
  __syncthreads();
  if (hf == 1){
    #pragma unroll
    for (int fn2 = 0; fn2 < 4; fn2++)
      *(f32x4*)&SLc[(ws*64 + l)*20 + fn2*4] = c[fn2];
  }
  __syncthreads();
  if (hf == 0){
    #pragma unroll
    for (int fn2 = 0; fn2 < 4; fn2++){
      f32x4 cp = *(const f32x4*)&SLc[(ws*64 + l)*20 + fn2*4];
      c[fn2] += cp;
    }
    #pragma unroll
    for (int fn2 = 0; fn2 < 4; fn2++){
      #pragma unroll
      for (int r = 0; r < 4; r++){
        int q = q0 + lg*4 + r;
        int d = fn2*16 + li;
        Ctx[(size_t)(b*1024 + q)*1024 + h*64 + d] = f2bf(c[fn2][r]);
      }
    }
  }
}

// ---------------- host launch ----------------
extern "C" void kernel_launch(void* const* d_in, const int* in_sizes, int n_in,
                              void* d_out, int out_size, void* d_ws, size_t ws_size,
                              hipStream_t stream)
{
  (void)in_sizes; (void)n_in; (void)out_size; (void)ws_size;
  const float* word = (const float*)d_in[0];
  const float* spk  = (const float*)d_in[1];
  const float* qww  = (const float*)d_in[3];
  const float* qwb  = (const float*)d_in[4];
  const float* kww  = (const float*)d_in[5];
  const float* kwb  = (const float*)d_in[6];
  const float* qsw  = (const float*)d_in[7];
  const float* qsb  = (const float*)d_in[8];
  const float* ksw  = (const float*)d_in[9];
  const float* ksb  = (const float*)d_in[10];
  const float* vw   = (const float*)d_in[11];
  const float* vb   = (const float*)d_in[12];
  const float* outw = (const float*)d_in[13];
  const float* outb = (const float*)d_in[14];
  const float* gamma= (const float*)d_in[15];
  const float* beta = (const float*)d_in[16];

  unsigned short* U = (unsigned short*)d_ws;
  unsigned short* XW    = U + E_XW;
  unsigned short* XS    = U + E_XS;
  unsigned short* WWORD = U + E_WWORD;
  unsigned short* WSPK  = U + E_WSPK;
  unsigned short* WOUT  = U + E_WOUT;
  unsigned short* PWORD = U + E_PWORD;
  unsigned short* PSPK  = U + E_PSPK;
  unsigned short* VT    = U + E_VT;
  unsigned short* CTX   = U + E_CTX;
  float* FB = (float*)(U + E_END);
  float* TS = FB + 5120;
  float* TC = TS + 32768;

  float* outp = (float*)d_out;
  float* attn = outp + (size_t)2*1024*1024;

  convert_all<<<4096, 256, 0, stream>>>(word, spk, qww, kww, vw, qsw, ksw, outw,
                                        qwb, kwb, vb, qsb, ksb, U, FB);
  gemm_qkv<<<640, 256, 0, stream>>>(XW, WWORD, XS, WSPK, FB, PWORD, PSPK);
  postproc<<<4608, 256, 0, stream>>>(PWORD, PSPK, gamma, beta, TS, TC, VT);
  attn_fused<<<512, 512, 0, stream>>>(PWORD, PSPK, VT, attn, CTX);
  gemm_out<<<256, 256, 0, stream>>>(CTX, WOUT, outb, outp);
}